// Round 4
// baseline (227.281 us; speedup 1.0000x reference)
//
#include <hip/hip_runtime.h>
#include <math.h>

#define NPATCHES 10
#define PATCH    100
#define BB       8
#define HL       112
#define WL       112
#define HH       1024
#define WH       1024
#define HW       (HL*WL)          // 12544
#define NSLICE   16
#define SLICE    (HW/NSLICE)      // 784
#define NSB      (BB*NSLICE)      // 128 slice blocks
#define NGB      (BB*NPATCHES*5)  // 400 gather blocks
#define MAGIC    0x13579BDF

// ws int-word layout:
//  [0..127]          per-slice flags
//  [128..135]        per-batch flags
//  [256 + sl*32 ..]  slice candidates (10 x {value bits, index})
//  [8192 + pn*4 ..]  per-(b,n) corners {cy, cx, scale_idx, pad}
#define WS_SLICE_FLAG(sl) (sl)
#define WS_BATCH_FLAG(b)  (128 + (b))
#define WS_CAND(sl)       (256 + (sl)*32)
#define WS_CORNER(pn)     (8192 + (pn)*4)

__device__ __forceinline__ unsigned rotl32(unsigned x, unsigned r){
  return (x << r) | (x >> (32u - r));
}

// JAX threefry2x32 with key = (0, 1)  (jax.random.key(1))
__device__ __forceinline__ void threefry2x32_key01(unsigned x0, unsigned x1,
                                                   unsigned &o0, unsigned &o1){
  const unsigned ks0 = 0u;
  const unsigned ks1 = 1u;
  const unsigned ks2 = 0x1BD11BDAu ^ ks0 ^ ks1;
  unsigned a = x0 + ks0;
  unsigned b = x1 + ks1;
#define TF_RND(r) { a += b; b = rotl32(b, (r)); b ^= a; }
  TF_RND(13u) TF_RND(15u) TF_RND(26u) TF_RND(6u)
  a += ks1; b += ks2 + 1u;
  TF_RND(17u) TF_RND(29u) TF_RND(16u) TF_RND(24u)
  a += ks2; b += ks0 + 2u;
  TF_RND(13u) TF_RND(15u) TF_RND(26u) TF_RND(6u)
  a += ks0; b += ks1 + 3u;
  TF_RND(17u) TF_RND(29u) TF_RND(16u) TF_RND(24u)
  a += ks1; b += ks2 + 4u;
  TF_RND(13u) TF_RND(15u) TF_RND(26u) TF_RND(6u)
  a += ks2; b += ks0 + 5u;
#undef TF_RND
  o0 = a; o1 = b;
}

__global__ __launch_bounds__(256)
void msp_fused_kernel(const float* __restrict__ x_highs,
                      const float* __restrict__ ats_map,
                      const int*   __restrict__ ats_index,
                      const float* __restrict__ scales,
                      float* __restrict__ out,
                      int*   __restrict__ ws)
{
  const int bid = blockIdx.x;
  const int t = threadIdx.x;

  if (bid >= NSB){
    // ---------------- gather role ----------------
    const int g     = bid - NSB;
    const int pn    = g / 5;          // b*NPATCHES + n
    const int chunk = g - pn * 5;     // 0..4 (20 rows each)
    const int b     = pn / NPATCHES;
    if (t == 0){
      while (__hip_atomic_load(&ws[WS_BATCH_FLAG(b)], __ATOMIC_ACQUIRE,
                               __HIP_MEMORY_SCOPE_AGENT) != MAGIC)
        __builtin_amdgcn_s_sleep(2);
    }
    __syncthreads();
    const int cy = ws[WS_CORNER(pn) + 0];
    const int cx = ws[WS_CORNER(pn) + 1];
    const int s  = ws[WS_CORNER(pn) + 2];
    const float* src = x_highs + (size_t)(s * BB + b) * ((size_t)HH * (WH * 3));
    float* dst = out + (size_t)pn * (PATCH * PATCH * 3);
    const int begin = chunk * 6000;   // 20 rows * 300 floats
    for (int f = begin + t * 4; f < begin + 6000; f += 1024){
      const int row = f / 300;
      const int col = f - row * 300;
      const float* sp = src + (size_t)(cy + row) * (WH * 3) + (size_t)cx * 3 + col;
      float4 v = make_float4(sp[0], sp[1], sp[2], sp[3]);
      *reinterpret_cast<float4*>(dst + f) = v;  // dst 16B-aligned (pn*30000, f%4==0)
    }
    return;
  }

  // ---------------- slice role ----------------
  const int b  = bid >> 4;
  const int sl = bid & 15;
  const int w  = t >> 6;
  const int l  = t & 63;
  const float* am = ats_map + (size_t)b * HW;

  __shared__ float swv[4];
  __shared__ float cvv[40];
  __shared__ int   cvi[40];
  __shared__ int   sel_s[NPATCHES];

  // 1. batch sum — identical op order in all 16 blocks of this batch -> same bits
  float ps = 0.0f;
  for (int i = t; i < HW; i += 256) ps += am[i];
  for (int d = 32; d > 0; d >>= 1) ps += __shfl_down(ps, d, 64);
  if (l == 0) swv[w] = ps;
  __syncthreads();
  const float S = swv[0] + swv[1] + swv[2] + swv[3];

  // 2. perturbed scores for this slice (<=4 per lane, register-resident)
  //    JAX partitionable threefry: bits(i) = xor(threefry2x32(key,(0,i)))
  const int base = sl * SLICE;
  float a[4];
  #pragma unroll
  for (int j = 0; j < 4; ++j){
    const int off = t + 256 * j;
    float v = -INFINITY;
    if (off < SLICE){
      const int i = base + off;
      unsigned o0, o1;
      threefry2x32_key01(0u, (unsigned)(b * HW + i), o0, o1);
      const unsigned bits = o0 ^ o1;
      const float u = __uint_as_float((bits >> 9) | 0x3f800000u) - 1.0f;
      const float g2 = -logf(-logf(u + 1e-10f) + 1e-10f);
      v = logf(am[i] / S + 1e-10f) + g2;
    }
    a[j] = v;
  }

  // 3. per-wave top-10, barrier-free (ties -> lowest global index)
  float lv = -INFINITY; int lj = 0;
  #pragma unroll
  for (int j = 0; j < 4; ++j) if (a[j] > lv){ lv = a[j]; lj = j; }

  for (int n = 0; n < NPATCHES; ++n){
    float bv = lv;
    int   bi = (lv == -INFINITY) ? 0x7fffffff : (base + w * 64 + l + 256 * lj);
    for (int d = 32; d > 0; d >>= 1){
      const float v2 = __shfl_down(bv, d, 64);
      const int   i2 = __shfl_down(bi, d, 64);
      if (v2 > bv || (v2 == bv && i2 < bi)){ bv = v2; bi = i2; }
    }
    bv = __shfl(bv, 0, 64);
    bi = __shfl(bi, 0, 64);
    if (l == 0){ cvv[w * 10 + n] = bv; cvi[w * 10 + n] = bi; }
    const int rel = bi - (base + w * 64);   // = l_owner + 256*j_owner
    if (bi != 0x7fffffff && (rel & 255) == l){
      a[rel >> 8] = -INFINITY;
      lv = -INFINITY; lj = 0;
      #pragma unroll
      for (int j = 0; j < 4; ++j) if (a[j] > lv){ lv = a[j]; lj = j; }
    }
  }
  __syncthreads();

  // 4. wave 0: merge 40 wave-candidates -> slice top-10 -> ws + release flag
  if (w == 0){
    float mv = -INFINITY; int mi = 0x7fffffff;
    if (l < 40){ mv = cvv[l]; mi = cvi[l]; }
    int* wc = ws + WS_CAND(bid);
    for (int n = 0; n < NPATCHES; ++n){
      float bv = mv; int bi = mi;
      for (int d = 32; d > 0; d >>= 1){
        const float v2 = __shfl_down(bv, d, 64);
        const int   i2 = __shfl_down(bi, d, 64);
        if (v2 > bv || (v2 == bv && i2 < bi)){ bv = v2; bi = i2; }
      }
      bv = __shfl(bv, 0, 64);
      bi = __shfl(bi, 0, 64);
      if (l == 0){ wc[2*n] = __float_as_int(bv); wc[2*n + 1] = bi; }
      if (mi == bi && mv == bv){ mv = -INFINITY; mi = 0x7fffffff; }
    }
    if (l == 0)
      __hip_atomic_store(&ws[WS_SLICE_FLAG(bid)], MAGIC, __ATOMIC_RELEASE,
                         __HIP_MEMORY_SCOPE_AGENT);
  }

  // 5. sl==0 block: wait for siblings, merge 160 candidates, emit outputs+corners
  if (sl == 0){
    if (t == 0){
      for (int s2 = 1; s2 < NSLICE; ++s2)
        while (__hip_atomic_load(&ws[WS_SLICE_FLAG(b * 16 + s2)], __ATOMIC_ACQUIRE,
                                 __HIP_MEMORY_SCOPE_AGENT) != MAGIC)
          __builtin_amdgcn_s_sleep(2);
    }
    __syncthreads();
    if (w == 0){
      float mv[3]; int mi[3];
      #pragma unroll
      for (int c = 0; c < 3; ++c){
        const int id = l + 64 * c;
        if (id < NSLICE * NPATCHES){
          const int* wc = ws + WS_CAND(b * 16 + id / 10);
          const int k = id - (id / 10) * 10;
          mv[c] = __int_as_float(wc[2*k]);
          mi[c] = wc[2*k + 1];
        } else { mv[c] = -INFINITY; mi[c] = 0x7fffffff; }
      }
      float cv = -INFINITY; int ci = 0x7fffffff;
      #pragma unroll
      for (int c = 0; c < 3; ++c)
        if (mv[c] > cv || (mv[c] == cv && mi[c] < ci)){ cv = mv[c]; ci = mi[c]; }

      for (int n = 0; n < NPATCHES; ++n){
        float bv = cv; int bi = ci;
        for (int d = 32; d > 0; d >>= 1){
          const float v2 = __shfl_down(bv, d, 64);
          const int   i2 = __shfl_down(bi, d, 64);
          if (v2 > bv || (v2 == bv && i2 < bi)){ bv = v2; bi = i2; }
        }
        bv = __shfl(bv, 0, 64);
        bi = __shfl(bi, 0, 64);
        if (l == 0) sel_s[n] = bi;
        bool had = false;
        #pragma unroll
        for (int c = 0; c < 3; ++c)
          if (mi[c] == bi && mv[c] == bv){ mv[c] = -INFINITY; had = true; }
        if (had){
          cv = -INFINITY; ci = 0x7fffffff;
          #pragma unroll
          for (int c = 0; c < 3; ++c)
            if (mv[c] > cv || (mv[c] == cv && mi[c] < ci)){ cv = mv[c]; ci = mi[c]; }
        }
      }
    }
    __syncthreads();

    if (t < NPATCHES){
      const int n = t;
      const int idx = sel_s[n];
      const float att = am[idx] / S;
      const int iy = idx / WL;
      const float sy = (float)iy;
      const float sx = (float)(idx - iy * WL);
      const int si = ats_index[(size_t)b * HW + idx];
      const float sc = scales[si];
      const float cyf = sy / sc;
      const float cxf = sx / sc;
      const float ratio = (float)(924.0 / 111.0);  // (HH-PATCH)/(HL-1), f64->f32
      int corner_y = (int)rintf(cyf * ratio);      // round-half-even = jnp.round
      int corner_x = (int)rintf(cxf * ratio);
      corner_y = min(max(corner_y, 0), HH - PATCH);
      corner_x = min(max(corner_x, 0), WH - PATCH);

      float* out_att = out + (size_t)BB * NPATCHES * PATCH * PATCH * 3;
      float* out_off = out_att + BB * NPATCHES;
      float* out_smp = out_off + BB * NPATCHES * 2;
      out_att[b * NPATCHES + n] = att;
      out_off[(b * NPATCHES + n) * 2 + 0] = 0.0f;  // RECEPTIVE_FIELD/2
      out_off[(b * NPATCHES + n) * 2 + 1] = 0.0f;
      out_smp[(b * NPATCHES + n) * 2 + 0] = cyf;
      out_smp[(b * NPATCHES + n) * 2 + 1] = cxf;

      int* cw = ws + WS_CORNER(b * NPATCHES + n);
      cw[0] = corner_y; cw[1] = corner_x; cw[2] = si; cw[3] = 0;
    }
    __syncthreads();
    if (t == 0){
      __threadfence();
      __hip_atomic_store(&ws[WS_BATCH_FLAG(b)], MAGIC, __ATOMIC_RELEASE,
                         __HIP_MEMORY_SCOPE_AGENT);
    }
  }
}

extern "C" void kernel_launch(void* const* d_in, const int* in_sizes, int n_in,
                              void* d_out, int out_size, void* d_ws, size_t ws_size,
                              hipStream_t stream)
{
  // setup_inputs order: x_lows(0, unused), x_highs(1), ats_map(2), ats_index(3), scales(4)
  const float* x_highs   = (const float*)d_in[1];
  const float* ats_map   = (const float*)d_in[2];
  const int*   ats_index = (const int*)d_in[3];
  const float* scales    = (const float*)d_in[4];
  float* out = (float*)d_out;
  int*   ws  = (int*)d_ws;

  hipLaunchKernelGGL(msp_fused_kernel, dim3(NSB + NGB), dim3(256), 0, stream,
                     x_highs, ats_map, ats_index, scales, out, ws);
}

// Round 5
// 38.592 us; speedup vs baseline: 5.8893x; 5.8893x over previous
//
#include <hip/hip_runtime.h>
#include <math.h>

#define NPATCHES 10
#define PATCH    100
#define BB       8
#define HL       112
#define WL       112
#define HH       1024
#define WH       1024
#define HW       (HL*WL)        // 12544
#define WSLICE   784            // HW / 16 waves
#define NW       16             // waves per block

__device__ __forceinline__ unsigned rotl32(unsigned x, unsigned r){
  return (x << r) | (x >> (32u - r));
}

// JAX threefry2x32 with key = (0, 1)  (jax.random.key(1))
__device__ __forceinline__ void threefry2x32_key01(unsigned x0, unsigned x1,
                                                   unsigned &o0, unsigned &o1){
  const unsigned ks0 = 0u;
  const unsigned ks1 = 1u;
  const unsigned ks2 = 0x1BD11BDAu ^ ks0 ^ ks1;
  unsigned a = x0 + ks0;
  unsigned b = x1 + ks1;
#define TF_RND(r) { a += b; b = rotl32(b, (r)); b ^= a; }
  TF_RND(13u) TF_RND(15u) TF_RND(26u) TF_RND(6u)
  a += ks1; b += ks2 + 1u;
  TF_RND(17u) TF_RND(29u) TF_RND(16u) TF_RND(24u)
  a += ks2; b += ks0 + 2u;
  TF_RND(13u) TF_RND(15u) TF_RND(26u) TF_RND(6u)
  a += ks0; b += ks1 + 3u;
  TF_RND(17u) TF_RND(29u) TF_RND(16u) TF_RND(24u)
  a += ks1; b += ks2 + 4u;
  TF_RND(13u) TF_RND(15u) TF_RND(26u) TF_RND(6u)
  a += ks2; b += ks0 + 5u;
#undef TF_RND
  o0 = a; o1 = b;
}

// One block per (batch, patch). Each block redundantly computes its batch's
// top-10 (identical code+input across the 10 sibling blocks -> identical
// results), then gathers only its own patch. No inter-block communication.
__global__ __launch_bounds__(1024)
void msp_fused_kernel(const float* __restrict__ x_highs,
                      const float* __restrict__ ats_map,
                      const int*   __restrict__ ats_index,
                      const float* __restrict__ scales,
                      float* __restrict__ out)
{
  __shared__ float swv[NW];
  __shared__ float cand_v[NW * NPATCHES];
  __shared__ int   cand_i[NW * NPATCHES];
  __shared__ float s_sum;
  __shared__ int   sel[NPATCHES];
  __shared__ int   c_cy, c_cx, c_si;

  const int pn = blockIdx.x;        // b*NPATCHES + n
  const int b  = pn / NPATCHES;
  const int n  = pn - b * NPATCHES;
  const int t  = threadIdx.x;
  const int w  = t >> 6;            // wave 0..15
  const int l  = t & 63;            // lane
  const int base = w * WSLICE;
  const float* am = ats_map + (size_t)b * HW;

  // ---- 1. load slice into regs + per-batch sum (round-3 verbatim) ----
  float a[13];
  float ps = 0.0f;
  #pragma unroll
  for (int j = 0; j < 13; ++j){
    const int off = l + 64 * j;
    float x = 0.0f;
    if (off < WSLICE) x = am[base + off];
    a[j] = x;
    ps += x;
  }
  for (int d = 32; d > 0; d >>= 1) ps += __shfl_down(ps, d, 64);
  if (l == 0) swv[w] = ps;
  __syncthreads();
  if (t == 0){
    float s = 0.0f;
    for (int k = 0; k < NW; ++k) s += swv[k];
    s_sum = s;
  }
  __syncthreads();
  const float S = s_sum;

  // ---- 2. perturbed scores (JAX partitionable threefry) ----
  #pragma unroll
  for (int j = 0; j < 13; ++j){
    const int off = l + 64 * j;
    const int i = base + off;
    unsigned o0, o1;
    threefry2x32_key01(0u, (unsigned)(b * HW + i), o0, o1);
    const unsigned bits = o0 ^ o1;
    const float u = __uint_as_float((bits >> 9) | 0x3f800000u) - 1.0f;
    const float g = -logf(-logf(u + 1e-10f) + 1e-10f);
    const float att = a[j] / S;
    const float sc = logf(att + 1e-10f) + g;
    a[j] = (off < WSLICE) ? sc : -INFINITY;
  }

  float lv = -INFINITY; int lj = 0;
  #pragma unroll
  for (int j = 0; j < 13; ++j) if (a[j] > lv){ lv = a[j]; lj = j; }

  // ---- 3. per-wave top-10, barrier-free ----
  for (int k = 0; k < NPATCHES; ++k){
    float bv = lv;
    int   bi = (lv == -INFINITY) ? 0x7fffffff : (base + l + 64 * lj);
    for (int d = 32; d > 0; d >>= 1){
      const float v2 = __shfl_down(bv, d, 64);
      const int   i2 = __shfl_down(bi, d, 64);
      if (v2 > bv || (v2 == bv && i2 < bi)){ bv = v2; bi = i2; }
    }
    bv = __shfl(bv, 0, 64);
    bi = __shfl(bi, 0, 64);
    if (l == 0){ cand_v[w * NPATCHES + k] = bv; cand_i[w * NPATCHES + k] = bi; }
    const int rel = bi - base;
    if (bi != 0x7fffffff && (rel & 63) == l){
      a[rel >> 6] = -INFINITY;
      lv = -INFINITY; lj = 0;
      #pragma unroll
      for (int j = 0; j < 13; ++j) if (a[j] > lv){ lv = a[j]; lj = j; }
    }
  }
  __syncthreads();

  // ---- 4. wave 0 merges 160 candidates -> global top-10 ----
  if (w == 0){
    float mv[3]; int mi[3];
    #pragma unroll
    for (int c = 0; c < 3; ++c){
      const int id = l + 64 * c;
      if (id < NW * NPATCHES){ mv[c] = cand_v[id]; mi[c] = cand_i[id]; }
      else { mv[c] = -INFINITY; mi[c] = 0x7fffffff; }
    }
    float cv = -INFINITY; int ci = 0x7fffffff;
    #pragma unroll
    for (int c = 0; c < 3; ++c)
      if (mv[c] > cv || (mv[c] == cv && mi[c] < ci)){ cv = mv[c]; ci = mi[c]; }

    for (int k = 0; k < NPATCHES; ++k){
      float bv = cv; int bi = ci;
      for (int d = 32; d > 0; d >>= 1){
        const float v2 = __shfl_down(bv, d, 64);
        const int   i2 = __shfl_down(bi, d, 64);
        if (v2 > bv || (v2 == bv && i2 < bi)){ bv = v2; bi = i2; }
      }
      bv = __shfl(bv, 0, 64);
      bi = __shfl(bi, 0, 64);
      if (l == 0) sel[k] = bi;
      bool had = false;
      #pragma unroll
      for (int c = 0; c < 3; ++c) if (mi[c] == bi && mv[c] == bv){ mv[c] = -INFINITY; had = true; }
      if (had){
        cv = -INFINITY; ci = 0x7fffffff;
        #pragma unroll
        for (int c = 0; c < 3; ++c)
          if (mv[c] > cv || (mv[c] == cv && mi[c] < ci)){ cv = mv[c]; ci = mi[c]; }
      }
    }
  }
  __syncthreads();

  // ---- 5. thread 0: this block's corner + small outputs ----
  if (t == 0){
    const int idx = sel[n];
    const float att = am[idx] / S;
    const int iy = idx / WL;
    const float sy = (float)iy;
    const float sx = (float)(idx - iy * WL);
    const int si = ats_index[(size_t)b * HW + idx];
    const float sc = scales[si];
    const float cyf = sy / sc;
    const float cxf = sx / sc;
    const float ratio = (float)(924.0 / 111.0);  // (HH-PATCH)/(HL-1), f64->f32
    int corner_y = (int)rintf(cyf * ratio);      // round-half-even = jnp.round
    int corner_x = (int)rintf(cxf * ratio);
    corner_y = min(max(corner_y, 0), HH - PATCH);
    corner_x = min(max(corner_x, 0), WH - PATCH);

    float* out_att = out + (size_t)BB * NPATCHES * PATCH * PATCH * 3;
    float* out_off = out_att + BB * NPATCHES;
    float* out_smp = out_off + BB * NPATCHES * 2;
    out_att[pn] = att;
    out_off[pn * 2 + 0] = 0.0f;                  // RECEPTIVE_FIELD/2
    out_off[pn * 2 + 1] = 0.0f;
    out_smp[pn * 2 + 0] = cyf;
    out_smp[pn * 2 + 1] = cxf;

    c_cy = corner_y; c_cx = corner_x; c_si = si;
  }
  __syncthreads();

  // ---- 6. gather this block's patch (30000 floats, float4 stores) ----
  const int cy = c_cy, cx = c_cx, s = c_si;
  const float* src = x_highs + (size_t)(s * BB + b) * ((size_t)HH * (WH * 3));
  float* dst = out + (size_t)pn * (PATCH * PATCH * 3);
  for (int f = t * 4; f < PATCH * PATCH * 3; f += 4096){
    const int row = f / 300;
    const int col = f - row * 300;
    const float* sp = src + (size_t)(cy + row) * (WH * 3) + (size_t)cx * 3 + col;
    float4 v = make_float4(sp[0], sp[1], sp[2], sp[3]);
    *reinterpret_cast<float4*>(dst + f) = v;   // dst 16B-aligned: pn*30000 + f, f%4==0
  }
}

extern "C" void kernel_launch(void* const* d_in, const int* in_sizes, int n_in,
                              void* d_out, int out_size, void* d_ws, size_t ws_size,
                              hipStream_t stream)
{
  // setup_inputs order: x_lows(0, unused), x_highs(1), ats_map(2), ats_index(3), scales(4)
  const float* x_highs   = (const float*)d_in[1];
  const float* ats_map   = (const float*)d_in[2];
  const int*   ats_index = (const int*)d_in[3];
  const float* scales    = (const float*)d_in[4];
  float* out = (float*)d_out;

  hipLaunchKernelGGL(msp_fused_kernel, dim3(BB * NPATCHES), dim3(1024), 0, stream,
                     x_highs, ats_map, ats_index, scales, out);
}

// Round 6
// 35.494 us; speedup vs baseline: 6.4033x; 1.0873x over previous
//
#include <hip/hip_runtime.h>
#include <math.h>

#define NPATCHES 10
#define PATCH    100
#define BB       8
#define HL       112
#define WL       112
#define HH       1024
#define WH       1024
#define HW       (HL*WL)        // 12544
#define WSLICE   784            // HW / 16 waves
#define NW       16             // waves per block

#define LN2F 0.69314718055994530942f

__device__ __forceinline__ unsigned rotl32(unsigned x, unsigned r){
  return (x << r) | (x >> (32u - r));
}

// fast ln(x) via v_log_f32 (log2) * ln2 — ~2 ULP vs libm logf; selection
// gaps are O(0.01) so this cannot flip top-k order.
__device__ __forceinline__ float fast_ln(float x){
  return __log2f(x) * LN2F;
}

// JAX threefry2x32 with key = (0, 1)  (jax.random.key(1))
__device__ __forceinline__ void threefry2x32_key01(unsigned x0, unsigned x1,
                                                   unsigned &o0, unsigned &o1){
  const unsigned ks0 = 0u;
  const unsigned ks1 = 1u;
  const unsigned ks2 = 0x1BD11BDAu ^ ks0 ^ ks1;
  unsigned a = x0 + ks0;
  unsigned b = x1 + ks1;
#define TF_RND(r) { a += b; b = rotl32(b, (r)); b ^= a; }
  TF_RND(13u) TF_RND(15u) TF_RND(26u) TF_RND(6u)
  a += ks1; b += ks2 + 1u;
  TF_RND(17u) TF_RND(29u) TF_RND(16u) TF_RND(24u)
  a += ks2; b += ks0 + 2u;
  TF_RND(13u) TF_RND(15u) TF_RND(26u) TF_RND(6u)
  a += ks0; b += ks1 + 3u;
  TF_RND(17u) TF_RND(29u) TF_RND(16u) TF_RND(24u)
  a += ks1; b += ks2 + 4u;
  TF_RND(13u) TF_RND(15u) TF_RND(26u) TF_RND(6u)
  a += ks2; b += ks0 + 5u;
#undef TF_RND
  o0 = a; o1 = b;
}

// One block per (batch, patch). Each block redundantly computes its batch's
// top-10 (identical code+input across the 10 sibling blocks -> identical
// results), then gathers only its own patch. No inter-block communication.
__global__ __launch_bounds__(1024)
void msp_fused_kernel(const float* __restrict__ x_highs,
                      const float* __restrict__ ats_map,
                      const int*   __restrict__ ats_index,
                      const float* __restrict__ scales,
                      float* __restrict__ out)
{
  __shared__ float swv[NW];
  __shared__ float cand_v[NW * NPATCHES];
  __shared__ int   cand_i[NW * NPATCHES];
  __shared__ float s_sum;
  __shared__ int   sel[NPATCHES];
  __shared__ int   c_cy, c_cx, c_si;

  const int pn = blockIdx.x;        // b*NPATCHES + n
  const int b  = pn / NPATCHES;
  const int n  = pn - b * NPATCHES;
  const int t  = threadIdx.x;
  const int w  = t >> 6;            // wave 0..15
  const int l  = t & 63;            // lane
  const int base = w * WSLICE;
  const float* am = ats_map + (size_t)b * HW;

  // ---- 1. load slice into regs + per-batch sum ----
  float a[13];
  float ps = 0.0f;
  #pragma unroll
  for (int j = 0; j < 13; ++j){
    const int off = l + 64 * j;
    float x = 0.0f;
    if (off < WSLICE) x = am[base + off];
    a[j] = x;
    ps += x;
  }
  for (int d = 32; d > 0; d >>= 1) ps += __shfl_down(ps, d, 64);
  if (l == 0) swv[w] = ps;
  __syncthreads();
  if (t == 0){
    float s = 0.0f;
    for (int k = 0; k < NW; ++k) s += swv[k];
    s_sum = s;
  }
  __syncthreads();
  const float S = s_sum;
  const float Sinv = 1.0f / S;     // selection only; output att uses exact /S

  // ---- 2. perturbed scores (JAX partitionable threefry + fast logs) ----
  #pragma unroll
  for (int j = 0; j < 13; ++j){
    const int off = l + 64 * j;
    const int i = base + off;
    unsigned o0, o1;
    threefry2x32_key01(0u, (unsigned)(b * HW + i), o0, o1);
    const unsigned bits = o0 ^ o1;
    const float u = __uint_as_float((bits >> 9) | 0x3f800000u) - 1.0f;
    const float l1 = fast_ln(u + 1e-10f);            // ln(u+1e-10)
    const float g  = -fast_ln(-l1 + 1e-10f);         // gumbel
    const float sc = fast_ln(a[j] * Sinv + 1e-10f) + g;
    a[j] = (off < WSLICE) ? sc : -INFINITY;
  }

  float lv = -INFINITY; int lj = 0;
  #pragma unroll
  for (int j = 0; j < 13; ++j) if (a[j] > lv){ lv = a[j]; lj = j; }

  // ---- 3. per-wave top-10, barrier-free ----
  for (int k = 0; k < NPATCHES; ++k){
    float bv = lv;
    int   bi = (lv == -INFINITY) ? 0x7fffffff : (base + l + 64 * lj);
    for (int d = 32; d > 0; d >>= 1){
      const float v2 = __shfl_down(bv, d, 64);
      const int   i2 = __shfl_down(bi, d, 64);
      if (v2 > bv || (v2 == bv && i2 < bi)){ bv = v2; bi = i2; }
    }
    bv = __shfl(bv, 0, 64);
    bi = __shfl(bi, 0, 64);
    if (l == 0){ cand_v[w * NPATCHES + k] = bv; cand_i[w * NPATCHES + k] = bi; }
    const int rel = bi - base;
    if (bi != 0x7fffffff && (rel & 63) == l){
      a[rel >> 6] = -INFINITY;
      lv = -INFINITY; lj = 0;
      #pragma unroll
      for (int j = 0; j < 13; ++j) if (a[j] > lv){ lv = a[j]; lj = j; }
    }
  }
  __syncthreads();

  // ---- 4. wave 0 merges 160 candidates -> global top-10 ----
  if (w == 0){
    float mv[3]; int mi[3];
    #pragma unroll
    for (int c = 0; c < 3; ++c){
      const int id = l + 64 * c;
      if (id < NW * NPATCHES){ mv[c] = cand_v[id]; mi[c] = cand_i[id]; }
      else { mv[c] = -INFINITY; mi[c] = 0x7fffffff; }
    }
    float cv = -INFINITY; int ci = 0x7fffffff;
    #pragma unroll
    for (int c = 0; c < 3; ++c)
      if (mv[c] > cv || (mv[c] == cv && mi[c] < ci)){ cv = mv[c]; ci = mi[c]; }

    for (int k = 0; k < NPATCHES; ++k){
      float bv = cv; int bi = ci;
      for (int d = 32; d > 0; d >>= 1){
        const float v2 = __shfl_down(bv, d, 64);
        const int   i2 = __shfl_down(bi, d, 64);
        if (v2 > bv || (v2 == bv && i2 < bi)){ bv = v2; bi = i2; }
      }
      bv = __shfl(bv, 0, 64);
      bi = __shfl(bi, 0, 64);
      if (l == 0) sel[k] = bi;
      bool had = false;
      #pragma unroll
      for (int c = 0; c < 3; ++c) if (mi[c] == bi && mv[c] == bv){ mv[c] = -INFINITY; had = true; }
      if (had){
        cv = -INFINITY; ci = 0x7fffffff;
        #pragma unroll
        for (int c = 0; c < 3; ++c)
          if (mv[c] > cv || (mv[c] == cv && mi[c] < ci)){ cv = mv[c]; ci = mi[c]; }
      }
    }
  }
  __syncthreads();

  // ---- 5. thread 0: this block's corner + small outputs ----
  if (t == 0){
    const int idx = sel[n];
    const float att = am[idx] / S;               // exact reference path
    const int iy = idx / WL;
    const float sy = (float)iy;
    const float sx = (float)(idx - iy * WL);
    const int si = ats_index[(size_t)b * HW + idx];
    const float sc = scales[si];
    const float cyf = sy / sc;
    const float cxf = sx / sc;
    const float ratio = (float)(924.0 / 111.0);  // (HH-PATCH)/(HL-1), f64->f32
    int corner_y = (int)rintf(cyf * ratio);      // round-half-even = jnp.round
    int corner_x = (int)rintf(cxf * ratio);
    corner_y = min(max(corner_y, 0), HH - PATCH);
    corner_x = min(max(corner_x, 0), WH - PATCH);

    float* out_att = out + (size_t)BB * NPATCHES * PATCH * PATCH * 3;
    float* out_off = out_att + BB * NPATCHES;
    float* out_smp = out_off + BB * NPATCHES * 2;
    out_att[pn] = att;
    out_off[pn * 2 + 0] = 0.0f;                  // RECEPTIVE_FIELD/2
    out_off[pn * 2 + 1] = 0.0f;
    out_smp[pn * 2 + 0] = cyf;
    out_smp[pn * 2 + 1] = cxf;

    c_cy = corner_y; c_cx = corner_x; c_si = si;
  }
  __syncthreads();

  // ---- 6. gather this block's patch (30000 floats, float4 stores) ----
  const int cy = c_cy, cx = c_cx, s = c_si;
  const float* src = x_highs + (size_t)(s * BB + b) * ((size_t)HH * (WH * 3));
  float* dst = out + (size_t)pn * (PATCH * PATCH * 3);
  for (int f = t * 4; f < PATCH * PATCH * 3; f += 4096){
    const int row = f / 300;
    const int col = f - row * 300;
    const float* sp = src + (size_t)(cy + row) * (WH * 3) + (size_t)cx * 3 + col;
    float4 v = make_float4(sp[0], sp[1], sp[2], sp[3]);
    *reinterpret_cast<float4*>(dst + f) = v;   // dst 16B-aligned: pn*30000 + f, f%4==0
  }
}

extern "C" void kernel_launch(void* const* d_in, const int* in_sizes, int n_in,
                              void* d_out, int out_size, void* d_ws, size_t ws_size,
                              hipStream_t stream)
{
  // setup_inputs order: x_lows(0, unused), x_highs(1), ats_map(2), ats_index(3), scales(4)
  const float* x_highs   = (const float*)d_in[1];
  const float* ats_map   = (const float*)d_in[2];
  const int*   ats_index = (const int*)d_in[3];
  const float* scales    = (const float*)d_in[4];
  float* out = (float*)d_out;

  hipLaunchKernelGGL(msp_fused_kernel, dim3(BB * NPATCHES), dim3(1024), 0, stream,
                     x_highs, ats_map, ats_index, scales, out);
}

// Round 7
// 34.903 us; speedup vs baseline: 6.5118x; 1.0169x over previous
//
#include <hip/hip_runtime.h>
#include <math.h>

#define NPATCHES 10
#define PATCH    100
#define BB       8
#define HL       112
#define WL       112
#define HH       1024
#define WH       1024
#define HW       (HL*WL)        // 12544
#define WSLICE   784            // HW / 16 waves
#define NW       16             // waves per block

#define LN2F 0.69314718055994530942f

__device__ __forceinline__ unsigned rotl32(unsigned x, unsigned r){
  return (x << r) | (x >> (32u - r));
}

// fast ln(x) via v_log_f32 (log2) * ln2 — ~2 ULP vs libm logf; selection
// gaps are O(0.01) so this cannot flip top-k order.
__device__ __forceinline__ float fast_ln(float x){
  return __log2f(x) * LN2F;
}

// JAX threefry2x32 with key = (0, 1)  (jax.random.key(1))
__device__ __forceinline__ void threefry2x32_key01(unsigned x0, unsigned x1,
                                                   unsigned &o0, unsigned &o1){
  const unsigned ks0 = 0u;
  const unsigned ks1 = 1u;
  const unsigned ks2 = 0x1BD11BDAu ^ ks0 ^ ks1;
  unsigned a = x0 + ks0;
  unsigned b = x1 + ks1;
#define TF_RND(r) { a += b; b = rotl32(b, (r)); b ^= a; }
  TF_RND(13u) TF_RND(15u) TF_RND(26u) TF_RND(6u)
  a += ks1; b += ks2 + 1u;
  TF_RND(17u) TF_RND(29u) TF_RND(16u) TF_RND(24u)
  a += ks2; b += ks0 + 2u;
  TF_RND(13u) TF_RND(15u) TF_RND(26u) TF_RND(6u)
  a += ks0; b += ks1 + 3u;
  TF_RND(17u) TF_RND(29u) TF_RND(16u) TF_RND(24u)
  a += ks1; b += ks2 + 4u;
  TF_RND(13u) TF_RND(15u) TF_RND(26u) TF_RND(6u)
  a += ks2; b += ks0 + 5u;
#undef TF_RND
  o0 = a; o1 = b;
}

// Two blocks per (batch, patch). Each block redundantly computes its batch's
// top-10 (identical code+input across sibling blocks -> identical results),
// then gathers HALF of its patch (float4-aligned interleave). No inter-block
// communication; 160 blocks spread the gather over more CUs.
__global__ __launch_bounds__(1024)
void msp_fused_kernel(const float* __restrict__ x_highs,
                      const float* __restrict__ ats_map,
                      const int*   __restrict__ ats_index,
                      const float* __restrict__ scales,
                      float* __restrict__ out)
{
  __shared__ float swv[NW];
  __shared__ float cand_v[NW * NPATCHES];
  __shared__ int   cand_i[NW * NPATCHES];
  __shared__ float s_sum;
  __shared__ int   sel[NPATCHES];
  __shared__ int   c_cy, c_cx, c_si;

  const int bid  = blockIdx.x;
  const int pn   = bid >> 1;        // b*NPATCHES + n
  const int half = bid & 1;         // which half of the patch to gather
  const int b  = pn / NPATCHES;
  const int n  = pn - b * NPATCHES;
  const int t  = threadIdx.x;
  const int w  = t >> 6;            // wave 0..15
  const int l  = t & 63;            // lane
  const int base = w * WSLICE;
  const float* am = ats_map + (size_t)b * HW;

  // ---- 1. load slice into regs + per-batch sum ----
  float a[13];
  float ps = 0.0f;
  #pragma unroll
  for (int j = 0; j < 13; ++j){
    const int off = l + 64 * j;
    float x = 0.0f;
    if (off < WSLICE) x = am[base + off];
    a[j] = x;
    ps += x;
  }
  for (int d = 32; d > 0; d >>= 1) ps += __shfl_down(ps, d, 64);
  if (l == 0) swv[w] = ps;
  __syncthreads();
  if (t == 0){
    float s = 0.0f;
    for (int k = 0; k < NW; ++k) s += swv[k];
    s_sum = s;
  }
  __syncthreads();
  const float S = s_sum;
  const float Sinv = 1.0f / S;     // selection only; output att uses exact /S

  // ---- 2. perturbed scores (JAX partitionable threefry + fast logs) ----
  #pragma unroll
  for (int j = 0; j < 13; ++j){
    const int off = l + 64 * j;
    const int i = base + off;
    unsigned o0, o1;
    threefry2x32_key01(0u, (unsigned)(b * HW + i), o0, o1);
    const unsigned bits = o0 ^ o1;
    const float u = __uint_as_float((bits >> 9) | 0x3f800000u) - 1.0f;
    const float l1 = fast_ln(u + 1e-10f);            // ln(u+1e-10)
    const float g  = -fast_ln(-l1 + 1e-10f);         // gumbel
    const float sc = fast_ln(a[j] * Sinv + 1e-10f) + g;
    a[j] = (off < WSLICE) ? sc : -INFINITY;
  }

  float lv = -INFINITY; int lj = 0;
  #pragma unroll
  for (int j = 0; j < 13; ++j) if (a[j] > lv){ lv = a[j]; lj = j; }

  // ---- 3. per-wave top-10, barrier-free ----
  for (int k = 0; k < NPATCHES; ++k){
    float bv = lv;
    int   bi = (lv == -INFINITY) ? 0x7fffffff : (base + l + 64 * lj);
    for (int d = 32; d > 0; d >>= 1){
      const float v2 = __shfl_down(bv, d, 64);
      const int   i2 = __shfl_down(bi, d, 64);
      if (v2 > bv || (v2 == bv && i2 < bi)){ bv = v2; bi = i2; }
    }
    bv = __shfl(bv, 0, 64);
    bi = __shfl(bi, 0, 64);
    if (l == 0){ cand_v[w * NPATCHES + k] = bv; cand_i[w * NPATCHES + k] = bi; }
    const int rel = bi - base;
    if (bi != 0x7fffffff && (rel & 63) == l){
      a[rel >> 6] = -INFINITY;
      lv = -INFINITY; lj = 0;
      #pragma unroll
      for (int j = 0; j < 13; ++j) if (a[j] > lv){ lv = a[j]; lj = j; }
    }
  }
  __syncthreads();

  // ---- 4. wave 0 merges 160 candidates -> global top-10 ----
  if (w == 0){
    float mv[3]; int mi[3];
    #pragma unroll
    for (int c = 0; c < 3; ++c){
      const int id = l + 64 * c;
      if (id < NW * NPATCHES){ mv[c] = cand_v[id]; mi[c] = cand_i[id]; }
      else { mv[c] = -INFINITY; mi[c] = 0x7fffffff; }
    }
    float cv = -INFINITY; int ci = 0x7fffffff;
    #pragma unroll
    for (int c = 0; c < 3; ++c)
      if (mv[c] > cv || (mv[c] == cv && mi[c] < ci)){ cv = mv[c]; ci = mi[c]; }

    for (int k = 0; k < NPATCHES; ++k){
      float bv = cv; int bi = ci;
      for (int d = 32; d > 0; d >>= 1){
        const float v2 = __shfl_down(bv, d, 64);
        const int   i2 = __shfl_down(bi, d, 64);
        if (v2 > bv || (v2 == bv && i2 < bi)){ bv = v2; bi = i2; }
      }
      bv = __shfl(bv, 0, 64);
      bi = __shfl(bi, 0, 64);
      if (l == 0) sel[k] = bi;
      bool had = false;
      #pragma unroll
      for (int c = 0; c < 3; ++c) if (mi[c] == bi && mv[c] == bv){ mv[c] = -INFINITY; had = true; }
      if (had){
        cv = -INFINITY; ci = 0x7fffffff;
        #pragma unroll
        for (int c = 0; c < 3; ++c)
          if (mv[c] > cv || (mv[c] == cv && mi[c] < ci)){ cv = mv[c]; ci = mi[c]; }
      }
    }
  }
  __syncthreads();

  // ---- 5. thread 0: this block's corner + small outputs (half 0 only) ----
  if (t == 0){
    const int idx = sel[n];
    const int iy = idx / WL;
    const float sy = (float)iy;
    const float sx = (float)(idx - iy * WL);
    const int si = ats_index[(size_t)b * HW + idx];
    const float sc = scales[si];
    const float cyf = sy / sc;
    const float cxf = sx / sc;
    const float ratio = (float)(924.0 / 111.0);  // (HH-PATCH)/(HL-1), f64->f32
    int corner_y = (int)rintf(cyf * ratio);      // round-half-even = jnp.round
    int corner_x = (int)rintf(cxf * ratio);
    corner_y = min(max(corner_y, 0), HH - PATCH);
    corner_x = min(max(corner_x, 0), WH - PATCH);

    if (half == 0){
      const float att = am[idx] / S;             // exact reference path
      float* out_att = out + (size_t)BB * NPATCHES * PATCH * PATCH * 3;
      float* out_off = out_att + BB * NPATCHES;
      float* out_smp = out_off + BB * NPATCHES * 2;
      out_att[pn] = att;
      out_off[pn * 2 + 0] = 0.0f;                // RECEPTIVE_FIELD/2
      out_off[pn * 2 + 1] = 0.0f;
      out_smp[pn * 2 + 0] = cyf;
      out_smp[pn * 2 + 1] = cxf;
    }
    c_cy = corner_y; c_cx = corner_x; c_si = si;
  }
  __syncthreads();

  // ---- 6. gather this block's half-patch (float4-aligned interleave) ----
  const int cy = c_cy, cx = c_cx, s = c_si;
  const float* src = x_highs + (size_t)(s * BB + b) * ((size_t)HH * (WH * 3));
  float* dst = out + (size_t)pn * (PATCH * PATCH * 3);
  for (int f = half * 4096 + t * 4; f < PATCH * PATCH * 3; f += 8192){
    const int row = f / 300;
    const int col = f - row * 300;
    const float* sp = src + (size_t)(cy + row) * (WH * 3) + (size_t)cx * 3 + col;
    float4 v = make_float4(sp[0], sp[1], sp[2], sp[3]);
    *reinterpret_cast<float4*>(dst + f) = v;   // dst 16B-aligned: pn*30000 + f, f%4==0
  }
}

extern "C" void kernel_launch(void* const* d_in, const int* in_sizes, int n_in,
                              void* d_out, int out_size, void* d_ws, size_t ws_size,
                              hipStream_t stream)
{
  // setup_inputs order: x_lows(0, unused), x_highs(1), ats_map(2), ats_index(3), scales(4)
  const float* x_highs   = (const float*)d_in[1];
  const float* ats_map   = (const float*)d_in[2];
  const int*   ats_index = (const int*)d_in[3];
  const float* scales    = (const float*)d_in[4];
  float* out = (float*)d_out;

  hipLaunchKernelGGL(msp_fused_kernel, dim3(BB * NPATCHES * 2), dim3(1024), 0, stream,
                     x_highs, ats_map, ats_index, scales, out);
}